// Round 1
// baseline (857.139 us; speedup 1.0000x reference)
//
#include <hip/hip_runtime.h>

typedef __attribute__((ext_vector_type(4))) float f4;
typedef __attribute__((ext_vector_type(8))) short s16x8;
typedef __attribute__((ext_vector_type(4))) unsigned short us4;
typedef unsigned short u16;
typedef unsigned int u32;

#define DEVI __device__ __forceinline__

DEVI u16 f2bf(float f){
    u32 u = __builtin_bit_cast(u32, f);
    u32 r = (u + 0x7fffu + ((u >> 16) & 1u)) >> 16;
    return (u16)r;
}
DEVI float bf2f(u16 h){
    u32 u = ((u32)h) << 16;
    return __builtin_bit_cast(float, u);
}
DEVI f4 mfma16(s16x8 a, s16x8 b, f4 c){
    return __builtin_amdgcn_mfma_f32_16x16x32_bf16(a, b, c, 0, 0, 0);
}

#define L2E 1.44269504088896340736f

// ---------------- weight bf16 cast (one launch) ----------------
// layout (u16 elems): [0,16384) conv2_w | [16384,32768) sa_wqk | [32768,98304) sa_wv
//                     [98304,163840) sa_wt | [163840,688128) fuse_w
__global__ __launch_bounds__(256) void k_cast(const float* w2, const float* wqk,
                                              const float* wv, const float* wt,
                                              const float* wf, u16* out){
    int i = blockIdx.x * 256 + threadIdx.x;
    float v;
    if(i < 16384)       v = w2[i];
    else if(i < 32768)  v = wqk[i - 16384];
    else if(i < 98304)  v = wv[i - 32768];
    else if(i < 163840) v = wt[i - 98304];
    else if(i < 688128) v = wf[i - 163840];
    else return;
    out[i] = f2bf(v);
}

// ---------------- stem conv1 (+bn+relu) -> h1 bf16 n-major [b][n][128] ----------------
__global__ __launch_bounds__(256) void k_stem1(const float* x, const float* w1,
                                               const float* g1, const float* b1, u16* h1tb){
    int t = blockIdx.x * 256 + threadIdx.x;      // 16*2048
    int b = t >> 11, n = t & 2047;
    const float* xb = x + (size_t)b * 3 * 2048 + n;
    float x0 = xb[0], x1 = xb[2048], x2 = xb[4096];
    u32* o = (u32*)(h1tb + (size_t)t * 128);
    #pragma unroll 8
    for(int c = 0; c < 128; c += 2){
        float a0 = fmaxf(g1[c]   * (w1[c*3+0]*x0 + w1[c*3+1]*x1 + w1[c*3+2]*x2) + b1[c],   0.f);
        float a1 = fmaxf(g1[c+1] * (w1[c*3+3]*x0 + w1[c*3+4]*x1 + w1[c*3+5]*x2) + b1[c+1], 0.f);
        o[c >> 1] = (u32)f2bf(a0) | ((u32)f2bf(a1) << 16);
    }
}

// ---------------- conv2 (+bn+relu): out fp32 + bf16, n-major ld=128 ----------------
__global__ __launch_bounds__(256) void k_conv2(const u16* h1tb, const u16* w2b,
                                               const float* g2, const float* b2,
                                               float* ht0, u16* htb0){
    int b = blockIdx.x >> 5;
    int n0 = (blockIdx.x & 31) << 6;
    int lane = threadIdx.x & 63, wv_ = threadIdx.x >> 6;
    int l15 = lane & 15, kg = lane >> 4;
    const u16* arow = h1tb + (size_t)(b*2048 + n0 + wv_*16 + l15) * 128 + kg*8;
    f4 acc[8];
    #pragma unroll
    for(int j=0;j<8;j++) acc[j] = (f4){0.f,0.f,0.f,0.f};
    #pragma unroll
    for(int ks=0; ks<4; ks++){
        s16x8 a = *(const s16x8*)(arow + ks*32);
        #pragma unroll
        for(int j=0;j<8;j++){
            s16x8 bb = *(const s16x8*)(w2b + (size_t)(j*16 + l15)*128 + ks*32 + kg*8);
            acc[j] = mfma16(a, bb, acc[j]);
        }
    }
    int nn0 = n0 + wv_*16 + kg*4;
    #pragma unroll
    for(int j=0;j<8;j++){
        int o = j*16 + l15;
        float gg = g2[o], be = b2[o];
        #pragma unroll
        for(int r=0;r<4;r++){
            float h = fmaxf(gg * acc[j][r] + be, 0.f);
            size_t idx = (size_t)(b*2048 + nn0 + r) * 128 + o;
            ht0[idx] = h;
            htb0[idx] = f2bf(h);
        }
    }
}

// ---------------- q projection: qb bf16 [b][n][32] ----------------
__global__ __launch_bounds__(256) void k_qproj(const u16* act, int lda, const u16* wqkb, u16* qb){
    int b = blockIdx.x >> 5;
    int n0 = (blockIdx.x & 31) << 6;
    int lane = threadIdx.x & 63, wv_ = threadIdx.x >> 6;
    int l15 = lane & 15, kg = lane >> 4;
    int n = n0 + wv_*16 + l15;
    const u16* brow = act + (size_t)(b*2048 + n) * lda + kg*8;
    f4 acc[2];
    acc[0] = (f4){0.f,0.f,0.f,0.f}; acc[1] = acc[0];
    #pragma unroll
    for(int ks=0; ks<4; ks++){
        s16x8 bfrag = *(const s16x8*)(brow + ks*32);
        #pragma unroll
        for(int f=0; f<2; f++){
            s16x8 afrag = *(const s16x8*)(wqkb + (size_t)(f*16 + l15)*128 + ks*32 + kg*8);
            acc[f] = mfma16(afrag, bfrag, acc[f]);
        }
    }
    #pragma unroll
    for(int f=0; f<2; f++){
        us4 pk;
        #pragma unroll
        for(int r=0;r<4;r++) pk[r] = f2bf(acc[f][r]);
        *(us4*)(qb + (size_t)(b*2048 + n)*32 + f*16 + kg*4) = pk;
    }
}

// ---------------- v projection (+bias): vb bf16 c-major [b][c][n] ----------------
__global__ __launch_bounds__(256) void k_vproj(const u16* act, int lda, const u16* wvb,
                                               const float* bv, u16* vb){
    int b = blockIdx.x >> 5;
    int n0 = (blockIdx.x & 31) << 6;
    int lane = threadIdx.x & 63, wv_ = threadIdx.x >> 6;
    int l15 = lane & 15, kg = lane >> 4;
    const u16* arow = act + (size_t)(b*2048 + n0 + wv_*16 + l15) * lda + kg*8;
    f4 acc[8];
    #pragma unroll
    for(int j=0;j<8;j++) acc[j] = (f4){0.f,0.f,0.f,0.f};
    #pragma unroll
    for(int ks=0; ks<4; ks++){
        s16x8 a = *(const s16x8*)(arow + ks*32);
        #pragma unroll
        for(int j=0;j<8;j++){
            s16x8 bb = *(const s16x8*)(wvb + (size_t)(j*16 + l15)*128 + ks*32 + kg*8);
            acc[j] = mfma16(a, bb, acc[j]);
        }
    }
    int nn0 = n0 + wv_*16 + kg*4;
    #pragma unroll
    for(int j=0;j<8;j++){
        int o = j*16 + l15;
        float bvo = bv[o];
        us4 pk;
        #pragma unroll
        for(int r=0;r<4;r++) pk[r] = f2bf(acc[j][r] + bvo);
        *(us4*)(vb + (size_t)(b*128 + o)*2048 + nn0) = pk;
    }
}

// ---------------- pass A: row max + 1/rowsum of softmax (online, MFMA e-tiles) ----------------
__global__ __launch_bounds__(256) void k_passA(const u16* qb, float* mrow, float* rlrow){
    int b = blockIdx.x >> 5;
    int i0 = (blockIdx.x & 31) << 6;
    int lane = threadIdx.x & 63, wv_ = threadIdx.x >> 6;
    int l15 = lane & 15, kg = lane >> 4;
    const u16* qbase = qb + (size_t)b * 2048 * 32;
    s16x8 af = *(const s16x8*)(qbase + (size_t)(i0 + wv_*16 + l15)*32 + kg*8);
    float m[4], s[4];
    #pragma unroll
    for(int r=0;r<4;r++){ m[r] = -1e30f; s[r] = 0.f; }
    const f4 z = {0.f,0.f,0.f,0.f};
    for(int j0=0; j0<2048; j0+=32){
        s16x8 b0 = *(const s16x8*)(qbase + (size_t)(j0 + l15)*32 + kg*8);
        s16x8 b1 = *(const s16x8*)(qbase + (size_t)(j0 + 16 + l15)*32 + kg*8);
        f4 e0 = mfma16(af, b0, z);
        f4 e1 = mfma16(af, b1, z);
        #pragma unroll
        for(int r=0;r<4;r++){
            float x0 = e0[r], x1 = e1[r];
            float mx = fmaxf(x0, x1);
            float mn = fmaxf(m[r], mx);
            s[r] = s[r]*exp2f((m[r]-mn)*L2E) + exp2f((x0-mn)*L2E) + exp2f((x1-mn)*L2E);
            m[r] = mn;
        }
    }
    #pragma unroll
    for(int d=1; d<16; d<<=1){
        #pragma unroll
        for(int r=0;r<4;r++){
            float mo = __shfl_xor(m[r], d);
            float so = __shfl_xor(s[r], d);
            float mn = fmaxf(m[r], mo);
            s[r] = s[r]*exp2f((m[r]-mn)*L2E) + so*exp2f((mo-mn)*L2E);
            m[r] = mn;
        }
    }
    if(l15 == 0){
        #pragma unroll
        for(int r=0;r<4;r++){
            int i = i0 + wv_*16 + kg*4 + r;
            mrow[b*2048 + i] = m[r];
            rlrow[b*2048 + i] = 1.0f / s[r];
        }
    }
}

// ---------------- pass B: x_r^T[n][c] = (V·P)/(1e-9+colsum), P in LDS ----------------
__global__ __launch_bounds__(256) void k_passB(const u16* qb, const u16* vb,
                                               const float* mrow, const float* rlrow,
                                               float* xrt){
    __shared__ u16 P[64*40];     // P^T [j 64][i 32, pad->40]
    __shared__ u16 V[128*40];    // V^T chunk [c 128][i 32, pad->40]
    __shared__ float csl[64];
    int b = blockIdx.x >> 5;
    int j0 = (blockIdx.x & 31) << 6;
    int tid = threadIdx.x;
    int lane = tid & 63, wv_ = tid >> 6;
    int l15 = lane & 15, kg = lane >> 4;
    const u16* qbase = qb + (size_t)b * 2048 * 32;
    const u16* vbase = vb + (size_t)b * 128 * 2048;
    const float* mr = mrow + b*2048;
    const float* rl = rlrow + b*2048;
    int jh = (wv_ >> 1) * 32;          // 0 / 32
    int il_base = (wv_ & 1) * 16;      // 0 / 16
    s16x8 eb0 = *(const s16x8*)(qbase + (size_t)(j0 + jh + l15)*32 + kg*8);
    s16x8 eb1 = *(const s16x8*)(qbase + (size_t)(j0 + jh + 16 + l15)*32 + kg*8);
    f4 acc[8];
    #pragma unroll
    for(int j=0;j<8;j++) acc[j] = (f4){0.f,0.f,0.f,0.f};
    float csp = 0.f;
    const f4 z = {0.f,0.f,0.f,0.f};
    for(int i0=0; i0<2048; i0+=32){
        __syncthreads();                       // protect P,V from prev readers
        #pragma unroll
        for(int p=0;p<2;p++){
            int q = tid + p*256;
            int c = q >> 2, part = q & 3;
            *(s16x8*)&V[c*40 + part*8] = *(const s16x8*)(vbase + (size_t)c*2048 + i0 + part*8);
        }
        s16x8 ea = *(const s16x8*)(qbase + (size_t)(i0 + il_base + l15)*32 + kg*8);
        f4 e0 = mfma16(ea, eb0, z);
        f4 e1 = mfma16(ea, eb1, z);
        int ib = i0 + il_base + kg*4;
        float mm0 = mr[ib+0], mm1 = mr[ib+1], mm2 = mr[ib+2], mm3 = mr[ib+3];
        float rr0 = rl[ib+0], rr1 = rl[ib+1], rr2 = rl[ib+2], rr3 = rl[ib+3];
        u32* Pw = (u32*)P;
        int pi0 = (jh + l15)*40 + il_base + kg*4;
        {
            float q0 = exp2f((e0[0]-mm0)*L2E)*rr0;
            float q1 = exp2f((e0[1]-mm1)*L2E)*rr1;
            float q2 = exp2f((e0[2]-mm2)*L2E)*rr2;
            float q3 = exp2f((e0[3]-mm3)*L2E)*rr3;
            Pw[(pi0>>1)+0] = (u32)f2bf(q0) | ((u32)f2bf(q1) << 16);
            Pw[(pi0>>1)+1] = (u32)f2bf(q2) | ((u32)f2bf(q3) << 16);
        }
        int pi1 = (jh + 16 + l15)*40 + il_base + kg*4;
        {
            float q0 = exp2f((e1[0]-mm0)*L2E)*rr0;
            float q1 = exp2f((e1[1]-mm1)*L2E)*rr1;
            float q2 = exp2f((e1[2]-mm2)*L2E)*rr2;
            float q3 = exp2f((e1[3]-mm3)*L2E)*rr3;
            Pw[(pi1>>1)+0] = (u32)f2bf(q0) | ((u32)f2bf(q1) << 16);
            Pw[(pi1>>1)+1] = (u32)f2bf(q2) | ((u32)f2bf(q3) << 16);
        }
        __syncthreads();
        int jl = wv_*16 + l15;
        s16x8 pa = *(const s16x8*)&P[jl*40 + kg*8];
        #pragma unroll
        for(int e=0;e<8;e++) csp += bf2f((u16)pa[e]);
        #pragma unroll
        for(int jc=0;jc<8;jc++){
            s16x8 vf = *(const s16x8*)&V[(jc*16 + l15)*40 + kg*8];
            acc[jc] = mfma16(pa, vf, acc[jc]);
        }
    }
    csp += __shfl_xor(csp, 16);
    csp += __shfl_xor(csp, 32);
    if(lane < 16) csl[wv_*16 + lane] = csp;
    __syncthreads();
    #pragma unroll
    for(int r=0;r<4;r++){
        int jrow = wv_*16 + kg*4 + r;
        float inv = 1.0f / (1e-9f + csl[jrow]);
        float* orow = xrt + (size_t)(b*2048 + j0 + jrow) * 128;
        #pragma unroll
        for(int jc=0;jc<8;jc++) orow[jc*16 + l15] = acc[jc][r] * inv;
    }
}

// ---------------- d = h - x_r -> bf16 n-major [b][n][128] ----------------
__global__ __launch_bounds__(256) void k_diff(const float* hprev, int ldh,
                                              const float* xrt, u16* dtb){
    int i = blockIdx.x*256 + threadIdx.x;     // 16*2048*32
    int bn = i >> 5, c4 = (i & 31) << 2;
    f4 h = *(const f4*)(hprev + (size_t)bn*ldh + c4);
    f4 xr = *(const f4*)(xrt + (size_t)bn*128 + c4);
    us4 d;
    #pragma unroll
    for(int r=0;r<4;r++) d[r] = f2bf(h[r] - xr[r]);
    *(us4*)(dtb + (size_t)bn*128 + c4) = d;
}

// ---------------- t-proj + residual update -> cat slices (fp32 + bf16, ld 512) ----------------
__global__ __launch_bounds__(256) void k_tail(const u16* dtb, const u16* wtb, const float* bt,
                                              const float* sg, const float* sb,
                                              const float* hprev, int ldh,
                                              float* catf_o, u16* catb_o){
    int b = blockIdx.x >> 5;
    int n0 = (blockIdx.x & 31) << 6;
    int lane = threadIdx.x & 63, wv_ = threadIdx.x >> 6;
    int l15 = lane & 15, kg = lane >> 4;
    const u16* arow = dtb + (size_t)(b*2048 + n0 + wv_*16 + l15) * 128 + kg*8;
    f4 acc[8];
    #pragma unroll
    for(int j=0;j<8;j++) acc[j] = (f4){0.f,0.f,0.f,0.f};
    #pragma unroll
    for(int ks=0; ks<4; ks++){
        s16x8 a = *(const s16x8*)(arow + ks*32);
        #pragma unroll
        for(int j=0;j<8;j++){
            s16x8 bb = *(const s16x8*)(wtb + (size_t)(j*16 + l15)*128 + ks*32 + kg*8);
            acc[j] = mfma16(a, bb, acc[j]);
        }
    }
    int nn0 = n0 + wv_*16 + kg*4;
    #pragma unroll
    for(int j=0;j<8;j++){
        int o = j*16 + l15;
        float bto = bt[o], gg = sg[o], be = sb[o];
        #pragma unroll
        for(int r=0;r<4;r++){
            int nn = nn0 + r;
            float t = acc[j][r] + bto;
            float hv = hprev[(size_t)(b*2048 + nn)*ldh + o];
            float hn = hv + fmaxf(gg*t + be, 0.f);
            size_t oi = (size_t)(b*2048 + nn)*512 + o;
            catf_o[oi] = hn;
            catb_o[oi] = f2bf(hn);
        }
    }
}

// ---------------- fuse conv (1024x512) + affine + leaky + max over n ----------------
__global__ __launch_bounds__(256) void k_fuse(const u16* catb, const u16* wfb,
                                              const float* fg, const float* fb, float* gout){
    __shared__ u16 Wl[32768];   // 64 rows x 512 bf16, xor-swizzled; red[] aliased at end
    int b = blockIdx.x >> 4;
    int o0 = (blockIdx.x & 15) << 6;
    int lane = threadIdx.x & 63, wv_ = threadIdx.x >> 6;
    int l15 = lane & 15, kg = lane >> 4;
    #pragma unroll
    for(int it=0; it<16; it++){
        int q = threadIdx.x + it*256;
        int row = q >> 6, part = q & 63;
        *(s16x8*)((char*)Wl + row*1024 + ((part*16) ^ ((row&7)<<4))) =
            *(const s16x8*)(wfb + (size_t)(o0+row)*512 + part*8);
    }
    __syncthreads();
    float vmax[4], fgv[4], fbv[4];
    #pragma unroll
    for(int j=0;j<4;j++){
        vmax[j] = -1e30f;
        fgv[j] = fg[o0 + j*16 + l15];
        fbv[j] = fb[o0 + j*16 + l15];
    }
    for(int n0=0; n0<2048; n0+=256){
        f4 acc[4][4];
        #pragma unroll
        for(int mi=0;mi<4;mi++)
            #pragma unroll
            for(int j=0;j<4;j++) acc[mi][j] = (f4){0.f,0.f,0.f,0.f};
        for(int ks=0; ks<16; ks++){
            s16x8 a[4];
            #pragma unroll
            for(int mi=0;mi<4;mi++)
                a[mi] = *(const s16x8*)(catb + (size_t)(b*2048 + n0 + wv_*64 + mi*16 + l15)*512 + ks*32 + kg*8);
            #pragma unroll
            for(int j=0;j<4;j++){
                int ol = j*16 + l15;
                s16x8 bb = *(const s16x8*)((const char*)Wl + ol*1024 + (((ks*4+kg)*16) ^ ((ol&7)<<4)));
                #pragma unroll
                for(int mi=0;mi<4;mi++) acc[mi][j] = mfma16(a[mi], bb, acc[mi][j]);
            }
        }
        #pragma unroll
        for(int mi=0;mi<4;mi++)
            #pragma unroll
            for(int j=0;j<4;j++)
                #pragma unroll
                for(int r=0;r<4;r++){
                    float f = fgv[j]*acc[mi][j][r] + fbv[j];
                    f = (f > 0.f) ? f : 0.2f*f;
                    vmax[j] = fmaxf(vmax[j], f);
                }
    }
    #pragma unroll
    for(int j=0;j<4;j++){
        vmax[j] = fmaxf(vmax[j], __shfl_xor(vmax[j], 16));
        vmax[j] = fmaxf(vmax[j], __shfl_xor(vmax[j], 32));
    }
    __syncthreads();                         // done reading Wl; alias as red
    float* red = (float*)Wl;                 // [4][64]
    if(lane < 16){
        #pragma unroll
        for(int j=0;j<4;j++) red[wv_*64 + j*16 + lane] = vmax[j];
    }
    __syncthreads();
    if(threadIdx.x < 64){
        float m = fmaxf(fmaxf(red[0*64+threadIdx.x], red[1*64+threadIdx.x]),
                        fmaxf(red[2*64+threadIdx.x], red[3*64+threadIdx.x]));
        gout[(size_t)b*1024 + o0 + threadIdx.x] = m;
    }
}

// ---------------- small dense layers ----------------
__global__ __launch_bounds__(256) void k_mlp(const float* in, const float* W, const float* bias,
                                             const float* gm, const float* bt, float* out,
                                             int IN, int OUT, int dorelu){
    int t = blockIdx.x*256 + threadIdx.x;
    int b = t / OUT, o = t % OUT;
    if(b >= 16) return;
    const f4* ir = (const f4*)(in + (size_t)b*IN);
    const f4* wr = (const f4*)(W + (size_t)o*IN);
    float s = 0.f;
    for(int k=0;k<IN/4;k++){
        f4 a = ir[k], w = wr[k];
        s += a[0]*w[0] + a[1]*w[1] + a[2]*w[2] + a[3]*w[3];
    }
    if(bias) s += bias[o];
    if(gm) s = gm[o]*s + bt[o];
    if(dorelu) s = fmaxf(s, 0.f);
    out[(size_t)b*OUT + o] = s;
}

// ---------------- workspace layout (bytes) ----------------
constexpr size_t OFF_WB   = 0;                          // 1,376,256 used
constexpr size_t OFF_H1TB = 2u*1024*1024;               // 8,388,608
constexpr size_t OFF_HT0  = OFF_H1TB + 8388608;         // 16,777,216
constexpr size_t OFF_HTB0 = OFF_HT0 + 16777216;         // 8,388,608
constexpr size_t OFF_QB   = OFF_HTB0 + 8388608;         // 2,097,152
constexpr size_t OFF_VB   = OFF_QB + 2097152;           // 8,388,608
constexpr size_t OFF_MROW = OFF_VB + 8388608;           // 131,072
constexpr size_t OFF_RL   = OFF_MROW + 131072;          // 131,072
constexpr size_t OFF_XRT  = OFF_RL + 131072;            // 16,777,216
constexpr size_t OFF_DTB  = OFF_XRT + 16777216;         // 8,388,608
constexpr size_t OFF_CATF = OFF_DTB + 8388608;          // 67,108,864
constexpr size_t OFF_CATB = OFF_CATF + 67108864;        // 33,554,432
constexpr size_t OFF_G    = OFF_CATB + 33554432;        // 65,536
constexpr size_t OFF_H1V  = OFF_G + 65536;              // 32,768
constexpr size_t OFF_H2V  = OFF_H1V + 32768;            // 16,384

extern "C" void kernel_launch(void* const* d_in, const int* in_sizes, int n_in,
                              void* d_out, int out_size, void* d_ws, size_t ws_size,
                              hipStream_t stream){
    const float* x       = (const float*)d_in[0];
    const float* conv1_w = (const float*)d_in[1];
    const float* bn1_g   = (const float*)d_in[2];
    const float* bn1_b   = (const float*)d_in[3];
    const float* conv2_w = (const float*)d_in[4];
    const float* bn2_g   = (const float*)d_in[5];
    const float* bn2_b   = (const float*)d_in[6];
    const float* sa_wqk  = (const float*)d_in[7];
    const float* sa_wv   = (const float*)d_in[8];
    const float* sa_bv   = (const float*)d_in[9];
    const float* sa_wt   = (const float*)d_in[10];
    const float* sa_bt   = (const float*)d_in[11];
    const float* sa_g    = (const float*)d_in[12];
    const float* sa_b    = (const float*)d_in[13];
    const float* fuse_w  = (const float*)d_in[14];
    const float* fuse_g  = (const float*)d_in[15];
    const float* fuse_b  = (const float*)d_in[16];
    const float* lin1_w  = (const float*)d_in[17];
    const float* bn6_g   = (const float*)d_in[18];
    const float* bn6_b   = (const float*)d_in[19];
    const float* lin2_w  = (const float*)d_in[20];
    const float* lin2_b  = (const float*)d_in[21];
    const float* bn7_g   = (const float*)d_in[22];
    const float* bn7_b   = (const float*)d_in[23];
    const float* lin3_w  = (const float*)d_in[24];
    const float* lin3_b  = (const float*)d_in[25];

    char* ws = (char*)d_ws;
    u16*   wb    = (u16*)(ws + OFF_WB);
    u16*   h1tb  = (u16*)(ws + OFF_H1TB);
    float* ht0   = (float*)(ws + OFF_HT0);
    u16*   htb0  = (u16*)(ws + OFF_HTB0);
    u16*   qbw   = (u16*)(ws + OFF_QB);
    u16*   vbw   = (u16*)(ws + OFF_VB);
    float* mrow  = (float*)(ws + OFF_MROW);
    float* rlrow = (float*)(ws + OFF_RL);
    float* xrt   = (float*)(ws + OFF_XRT);
    u16*   dtb   = (u16*)(ws + OFF_DTB);
    float* catf  = (float*)(ws + OFF_CATF);
    u16*   catb  = (u16*)(ws + OFF_CATB);
    float* gbuf  = (float*)(ws + OFF_G);
    float* h1v   = (float*)(ws + OFF_H1V);
    float* h2v   = (float*)(ws + OFF_H2V);

    k_cast <<<2688, 256, 0, stream>>>(conv2_w, sa_wqk, sa_wv, sa_wt, fuse_w, wb);
    k_stem1<<<128,  256, 0, stream>>>(x, conv1_w, bn1_g, bn1_b, h1tb);
    k_conv2<<<512,  256, 0, stream>>>(h1tb, wb /*w2b*/, bn2_g, bn2_b, ht0, htb0);

    for(int blk = 0; blk < 4; blk++){
        const u16*  actb  = (blk == 0) ? htb0 : (catb + (size_t)(blk-1)*128);
        int         lda   = (blk == 0) ? 128 : 512;
        const float* hprev = (blk == 0) ? ht0 : (catf + (size_t)(blk-1)*128);
        const u16* wqkb = wb + 16384 + blk*4096;
        const u16* wvb  = wb + 32768 + blk*16384;
        const u16* wtb  = wb + 98304 + blk*16384;

        k_qproj<<<512, 256, 0, stream>>>(actb, lda, wqkb, qbw);
        k_passA<<<512, 256, 0, stream>>>(qbw, mrow, rlrow);
        k_vproj<<<512, 256, 0, stream>>>(actb, lda, wvb, sa_bv + blk*128, vbw);
        k_passB<<<512, 256, 0, stream>>>(qbw, vbw, mrow, rlrow, xrt);
        k_diff <<<4096,256, 0, stream>>>(hprev, lda, xrt, dtb);
        k_tail <<<512, 256, 0, stream>>>(dtb, wtb, sa_bt + blk*128, sa_g + blk*128,
                                         sa_b + blk*128, hprev, lda,
                                         catf + (size_t)blk*128, catb + (size_t)blk*128);
    }

    k_fuse<<<256, 256, 0, stream>>>(catb, wb + 163840, fuse_g, fuse_b, gbuf);
    k_mlp <<<32,  256, 0, stream>>>(gbuf, lin1_w, nullptr, bn6_g, bn6_b, h1v, 1024, 512, 1);
    k_mlp <<<16,  256, 0, stream>>>(h1v, lin2_w, lin2_b, bn7_g, bn7_b, h2v, 512, 256, 1);
    k_mlp <<<3,   256, 0, stream>>>(h2v, lin3_w, lin3_b, nullptr, nullptr,
                                    (float*)d_out, 256, 40, 0);
}